// Round 1
// baseline (72.380 us; speedup 1.0000x reference)
//
#include <hip/hip_runtime.h>
#include <hip/hip_bf16.h>

// FreqCounter: out[b,i] = lookup[item_ids[b,i]]
// item_ids: (16384, 1000) int32 (harness passes integer inputs as int*)
// lookup:   (120000,) float32 — 480 KB, fits in per-XCD L2 (4 MiB)
// out:      (16384, 1000) float32
// user_ids (d_in[0]) unused, matching the reference forward.

__global__ void FreqCounter_68315749810839_kernel(
    const int* __restrict__ ids,
    const float* __restrict__ lookup,
    float* __restrict__ out,
    long n4)  // number of int4/float4 quads
{
    long i = (long)blockIdx.x * blockDim.x + threadIdx.x;
    const long stride = (long)gridDim.x * blockDim.x;
    const int4* __restrict__ ids4 = (const int4*)ids;
    float4* __restrict__ out4 = (float4*)out;

    for (; i < n4; i += stride) {
        int4 v = ids4[i];
        float4 r;
        r.x = lookup[v.x];
        r.y = lookup[v.y];
        r.z = lookup[v.z];
        r.w = lookup[v.w];
        out4[i] = r;
    }
}

extern "C" void kernel_launch(void* const* d_in, const int* in_sizes, int n_in,
                              void* d_out, int out_size, void* d_ws, size_t ws_size,
                              hipStream_t stream) {
    // setup_inputs order: user_ids, item_ids, lookup
    const int*   ids    = (const int*)d_in[1];
    const float* lookup = (const float*)d_in[2];
    float*       out    = (float*)d_out;

    const long n = (long)in_sizes[1];      // 16,384,000 — divisible by 4
    const long n4 = n / 4;

    const int block = 256;
    // Memory-bound: cap grid and grid-stride (G11). 2048 blocks = 8 blocks/CU.
    long want = (n4 + block - 1) / block;
    int grid = (int)(want < 2048 ? want : 2048);

    FreqCounter_68315749810839_kernel<<<grid, block, 0, stream>>>(ids, lookup, out, n4);
}